// Round 7
// baseline (149.783 us; speedup 1.0000x reference)
//
#include <hip/hip_runtime.h>

static constexpr int N_NODES = 50000;
static constexpr int N_EDGES = 800000;

static constexpr int NBK      = 98;      // buckets of 512 dst-nodes (dst>>9)
static constexpr int BCAP     = 10240;   // slots/bucket (mean 8192, +22 sigma)
static constexpr int MAXE     = BCAP / 512;   // 20 elems/thread in k_build
static constexpr int BIN_TILE = 2048;    // edges per k_bin block

typedef __attribute__((ext_vector_type(8))) short   bf16x8;
typedef __attribute__((ext_vector_type(4))) float   floatx4;

// f32 -> bf16 (RNE) as raw u16
__device__ __forceinline__ unsigned short f2b(float f) {
    union { float f; unsigned u; } v; v.f = f;
    unsigned r = v.u + 0x7FFFu + ((v.u >> 16) & 1u);
    return (unsigned short)(r >> 16);
}
__device__ __forceinline__ float blo(unsigned v) {
    union { unsigned u; float f; } c; c.u = v << 16; return c.f;
}
__device__ __forceinline__ float bhi(unsigned v) {
    union { unsigned u; float f; } c; c.u = v & 0xffff0000u; return c.f;
}
__device__ __forceinline__ unsigned pk2(float a, float b) {
    return (unsigned)f2b(a) | ((unsigned)f2b(b) << 16);
}

// ---------------------------------------------------------------------------
// Init bucket cursors
// ---------------------------------------------------------------------------
__global__ __launch_bounds__(128) void k_init(int* __restrict__ bcur)
{
    int i = threadIdx.x;
    if (i < NBK) bcur[i] = i * BCAP;
}

// ---------------------------------------------------------------------------
// Phase 1: bin edges into 98 dst-buckets, coalesced. epair packs
// (src<<9)|(dst&511) into ONE u32 (src<2^16). No node-indexed global atomics.
// ---------------------------------------------------------------------------
__global__ __launch_bounds__(256) void k_bin(
    const int* __restrict__ srcv, const int* __restrict__ dstv,
    int* __restrict__ bcur, unsigned* __restrict__ epair)
{
    __shared__ uint2 stage[BIN_TILE];      // 16 KB
    __shared__ int cnt[128];
    __shared__ int scn[128];
    __shared__ int pref[NBK];
    __shared__ int gbase[NBK];

    int tid   = threadIdx.x;
    int base  = blockIdx.x * BIN_TILE;
    int tileN = min(BIN_TILE, N_EDGES - base);

    if (tid < 128) cnt[tid] = 0;
    __syncthreads();

    int ss[8], dd[8], sl[8];
#pragma unroll
    for (int j = 0; j < 8; ++j) {
        int i = tid + j * 256;
        ss[j] = -1; dd[j] = 0; sl[j] = 0;
        if (i < tileN) {
            ss[j] = srcv[base + i];
            dd[j] = dstv[base + i];
            sl[j] = atomicAdd(&cnt[dd[j] >> 9], 1);   // LDS only
        }
    }
    __syncthreads();

    int own = (tid < 128) ? cnt[tid] : 0;
    if (tid < 128) scn[tid] = own;
    __syncthreads();
    for (int off = 1; off < 128; off <<= 1) {
        int t = 0;
        if (tid < 128 && tid >= off) t = scn[tid - off];
        __syncthreads();
        if (tid < 128) scn[tid] += t;
        __syncthreads();
    }
    if (tid < NBK) {
        pref[tid]  = scn[tid] - cnt[tid];
        gbase[tid] = atomicAdd(&bcur[tid], cnt[tid]);   // 98 atomics/block
    }
    __syncthreads();

#pragma unroll
    for (int j = 0; j < 8; ++j) {
        if (ss[j] >= 0) {
            int b = dd[j] >> 9;
            stage[pref[b] + sl[j]] = uint2{(unsigned)ss[j], (unsigned)dd[j]};
        }
    }
    __syncthreads();

    for (int i = tid; i < tileN; i += 256) {
        uint2 pd = stage[i];
        int b = (int)(pd.y >> 9);
        epair[(size_t)gbase[b] + (i - pref[b])] = (pd.x << 9) | (pd.y & 511u);
    }
}

// ---------------------------------------------------------------------------
// Phase 2: one block per bucket, SINGLE pass over epair: elems held in
// statically-indexed registers across the LDS histogram+scan, then scattered
// with zero atomics (pos = start[d] + slot captured at count time).
// ---------------------------------------------------------------------------
__global__ __launch_bounds__(512) void k_build(
    const unsigned* __restrict__ epair, const int* __restrict__ bcur,
    int* __restrict__ offsets, int* __restrict__ esrc)
{
    __shared__ int cnt[512];
    __shared__ int scn[512];
    __shared__ int start[512];
    __shared__ int s_base;

    int b = blockIdx.x;
    int t = threadIdx.x;
    int node0 = b << 9;
    int ncnt  = min(512, N_NODES - node0);
    int beg   = b * BCAP;
    int m     = bcur[b] - beg;

    cnt[t] = 0;
    __syncthreads();

    unsigned ev[MAXE]; int sl[MAXE];
#pragma unroll
    for (int j = 0; j < MAXE; ++j) {
        int i = t + j * 512;
        ev[j] = 0; sl[j] = -1;
        if (i < m) {
            ev[j] = epair[beg + i];
            sl[j] = atomicAdd(&cnt[ev[j] & 511u], 1);
        }
    }

    // bucket global base = total size of earlier buckets (first wave)
    if (t < 64) {
        int m0 = (t      < NBK) ? (bcur[t]      - t * BCAP)        : 0;
        int m1 = (t + 64 < NBK) ? (bcur[t + 64] - (t + 64) * BCAP) : 0;
        int pre = ((t < b) ? m0 : 0) + ((t + 64 < b) ? m1 : 0);
        for (int off = 1; off < 64; off <<= 1) pre += __shfl_xor(pre, off);
        if (t == 0) s_base = pre;
    }
    __syncthreads();

    // exclusive scan of cnt[0..511]
    int own = cnt[t];
    scn[t] = own;
    __syncthreads();
    for (int off = 1; off < 512; off <<= 1) {
        int v = (t >= off) ? scn[t - off] : 0;
        __syncthreads();
        scn[t] += v;
        __syncthreads();
    }
    int st = s_base + scn[t] - own;
    start[t] = st;
    if (t < ncnt) offsets[node0 + t] = st;
    if (b == 0 && t == 0) offsets[N_NODES] = N_EDGES;
    __syncthreads();

    // scatter src ids (no re-read, no atomics)
#pragma unroll
    for (int j = 0; j < MAXE; ++j) {
        if (sl[j] >= 0)
            esrc[start[ev[j] & 511u] + sl[j]] = (int)(ev[j] >> 9);
    }
}

// ---------------------------------------------------------------------------
// Layer-1 pre-projection (MFMA): u1 = x@Wrel1, r1 = x@Wroot1+b1, bf16
// sigma-order rows (p=(lane&15)*4+ct -> true col ct*16+(lane&15)).
// ---------------------------------------------------------------------------
__global__ __launch_bounds__(256) void k_pre1(
    const float* __restrict__ x,
    const float* __restrict__ Wrel,    // [64][64] f32
    const float* __restrict__ Wroot,   // [64][64] f32
    const float* __restrict__ bias,    // [64] f32
    unsigned short* __restrict__ u1,
    unsigned short* __restrict__ r1)
{
    int lane = threadIdx.x & 63;
    int c15  = lane & 15;
    int q    = lane >> 4;

    bf16x8 bf[2][4][2];
#pragma unroll
    for (int mat = 0; mat < 2; ++mat) {
        const float* W = mat ? Wroot : Wrel;
#pragma unroll
        for (int ct = 0; ct < 4; ++ct) {
            int c = ct * 16 + c15;
#pragma unroll
            for (int kf = 0; kf < 2; ++kf) {
                int kb = kf * 32 + q * 8;
                bf16x8 f;
#pragma unroll
                for (int j = 0; j < 8; ++j)
                    f[j] = (short)f2b(W[(kb + j) * 64 + c]);
                bf[mat][ct][kf] = f;
            }
        }
    }
    float bv[4];
#pragma unroll
    for (int ct = 0; ct < 4; ++ct) bv[ct] = bias[ct * 16 + c15];

    int tile = (blockIdx.x * blockDim.x + threadIdx.x) >> 6;
    if (tile * 16 >= N_NODES) return;
    int row0 = tile * 16;

    const float* xr = x + (size_t)(row0 + c15) * 64;
    bf16x8 a0, a1;
#pragma unroll
    for (int j = 0; j < 8; ++j) {
        a0[j] = (short)f2b(xr[q * 8 + j]);
        a1[j] = (short)f2b(xr[32 + q * 8 + j]);
    }

    floatx4 z = {0.f, 0.f, 0.f, 0.f};
    floatx4 acc[2][4];
#pragma unroll
    for (int mat = 0; mat < 2; ++mat)
#pragma unroll
        for (int ct = 0; ct < 4; ++ct) {
            floatx4 a = __builtin_amdgcn_mfma_f32_16x16x32_bf16(a0, bf[mat][ct][0], z, 0, 0, 0);
            acc[mat][ct] = __builtin_amdgcn_mfma_f32_16x16x32_bf16(a1, bf[mat][ct][1], a, 0, 0, 0);
        }

#pragma unroll
    for (int reg = 0; reg < 4; ++reg) {
        int row = row0 + q * 4 + reg;
        uint2 uu, rr;
        uu.x = pk2(acc[0][0][reg],          acc[0][1][reg]);
        uu.y = pk2(acc[0][2][reg],          acc[0][3][reg]);
        rr.x = pk2(acc[1][0][reg] + bv[0],  acc[1][1][reg] + bv[1]);
        rr.y = pk2(acc[1][2][reg] + bv[2],  acc[1][3][reg] + bv[3]);
        *reinterpret_cast<uint2*>(u1 + (size_t)row * 64 + c15 * 4) = uu;
        *reinterpret_cast<uint2*>(r1 + (size_t)row * 64 + c15 * 4) = rr;
    }
}

// ---------------------------------------------------------------------------
// FUSED aggregate-1 + pre-projection-2. Per node (one wave, grid-stride):
//   gather-sum u1[src] (sigma-order), h = relu(sum + r1)  [in registers],
//   then u2/r2 = h @ W2 via 64 const-lane shfl+FMA (weights in VGPRs).
// Outputs u2/r2 [N][32] bf16 in TRUE channel order. No h round-trip.
// ---------------------------------------------------------------------------
__global__ __launch_bounds__(256) void k_agg64p2(
    const unsigned short* __restrict__ u1,
    const unsigned short* __restrict__ r1,
    const int* __restrict__ offsets, const int* __restrict__ esrc,
    const float* __restrict__ Wrel,    // [64][32] f32
    const float* __restrict__ Wroot,   // [64][32] f32
    const float* __restrict__ bias,    // [32] f32
    unsigned short* __restrict__ u2,
    unsigned short* __restrict__ r2)
{
    int lane = threadIdx.x & 63;
    int c    = lane & 31;
    bool isRoot = lane >= 32;
    int j    = lane & 15;
    int slot = lane >> 4;

    // per-lane output column weights; w[p] = W[sigma(p)][c], sigma(p)=(p&3)*16+(p>>2)
    const float* W = isRoot ? Wroot : Wrel;
    float w[64];
#pragma unroll
    for (int p = 0; p < 64; ++p)
        w[p] = W[(((p & 3) << 4) + (p >> 2)) * 32 + c];
    float bv = isRoot ? bias[c] : 0.0f;
    unsigned short* dst = isRoot ? r2 : u2;

    int wid    = (blockIdx.x * blockDim.x + threadIdx.x) >> 6;
    int nwaves = (gridDim.x * blockDim.x) >> 6;
    for (int node = wid; node < N_NODES; node += nwaves) {
        int beg = offsets[node], end = offsets[node + 1];
        float s0 = 0.f, s1 = 0.f, s2 = 0.f, s3 = 0.f;
        for (int e = beg + slot; e < end; e += 4) {
            int s = esrc[e];
            uint2 v = *reinterpret_cast<const uint2*>(u1 + (size_t)s * 64 + j * 4);
            s0 += blo(v.x); s1 += bhi(v.x);
            s2 += blo(v.y); s3 += bhi(v.y);
        }
        s0 += __shfl_xor(s0, 32); s1 += __shfl_xor(s1, 32);
        s2 += __shfl_xor(s2, 32); s3 += __shfl_xor(s3, 32);
        s0 += __shfl_xor(s0, 16); s1 += __shfl_xor(s1, 16);
        s2 += __shfl_xor(s2, 16); s3 += __shfl_xor(s3, 16);
        // all 64 lanes now hold full sums for their j = lane&15 group
        uint2 rv = *reinterpret_cast<const uint2*>(r1 + (size_t)node * 64 + j * 4);
        float sv[4];
        sv[0] = fmaxf(s0 + blo(rv.x), 0.f);
        sv[1] = fmaxf(s1 + bhi(rv.x), 0.f);
        sv[2] = fmaxf(s2 + blo(rv.y), 0.f);
        sv[3] = fmaxf(s3 + bhi(rv.y), 0.f);
        float acc = bv;
#pragma unroll
        for (int p = 0; p < 64; ++p)
            acc += __shfl(sv[p & 3], p >> 2) * w[p];
        dst[(size_t)node * 32 + c] = f2b(acc);
    }
}

// ---------------------------------------------------------------------------
// Aggregate layer 2 (true channel order) -> row-major f32 out.
// ---------------------------------------------------------------------------
__global__ __launch_bounds__(256) void k_agg32(
    const unsigned short* __restrict__ u2,
    const unsigned short* __restrict__ r2,
    const int* __restrict__ offsets, const int* __restrict__ esrc,
    float* __restrict__ out)
{
    int lane = threadIdx.x & 63;
    int node = (blockIdx.x * blockDim.x + threadIdx.x) >> 6;
    if (node >= N_NODES) return;
    int j    = lane & 15;
    int slot = lane >> 4;
    int beg = offsets[node], end = offsets[node + 1];
    float s0 = 0.f, s1 = 0.f;
    for (int e = beg + slot; e < end; e += 4) {
        int s = esrc[e];
        unsigned v = *reinterpret_cast<const unsigned*>(u2 + (size_t)s * 32 + j * 2);
        s0 += blo(v); s1 += bhi(v);
    }
    s0 += __shfl_xor(s0, 32); s1 += __shfl_xor(s1, 32);
    s0 += __shfl_xor(s0, 16); s1 += __shfl_xor(s1, 16);
    if (lane < 16) {
        unsigned rv = *reinterpret_cast<const unsigned*>(r2 + (size_t)node * 32 + j * 2);
        float2 o;
        o.x = s0 + blo(rv);
        o.y = s1 + bhi(rv);
        *reinterpret_cast<float2*>(out + (size_t)node * 32 + j * 2) = o;
    }
}

extern "C" void kernel_launch(void* const* d_in, const int* in_sizes, int n_in,
                              void* d_out, int out_size, void* d_ws, size_t ws_size,
                              hipStream_t stream) {
    const float* x      = (const float*)d_in[0];
    const int*   ei     = (const int*)  d_in[1];
    const float* Wrel1  = (const float*)d_in[2];
    const float* Wroot1 = (const float*)d_in[3];
    const float* b1     = (const float*)d_in[4];
    const float* Wrel2  = (const float*)d_in[5];
    const float* Wroot2 = (const float*)d_in[6];
    const float* b2     = (const float*)d_in[7];
    float*       out    = (float*)d_out;

    const int* srcv = ei;
    const int* dstv = ei + N_EDGES;

    char* p = (char*)d_ws;
    auto alloc = [&](size_t bytes) {
        char* r = p;
        p += (bytes + 255) & ~(size_t)255;
        return r;
    };
    int*      offsets = (int*)     alloc(sizeof(int) * (N_NODES + 1));
    int*      bcur    = (int*)     alloc(sizeof(int) * NBK);
    unsigned* epair   = (unsigned*)alloc(sizeof(unsigned) * (size_t)NBK * BCAP);
    int*      esrc    = (int*)     alloc(sizeof(int) * N_EDGES);
    unsigned short* u1 = (unsigned short*)alloc(sizeof(short) * (size_t)N_NODES * 64);
    unsigned short* r1 = (unsigned short*)alloc(sizeof(short) * (size_t)N_NODES * 64);
    unsigned short* u2 = (unsigned short*)alloc(sizeof(short) * (size_t)N_NODES * 32);
    unsigned short* r2 = (unsigned short*)alloc(sizeof(short) * (size_t)N_NODES * 32);

    const int binBlocks  = (N_EDGES + BIN_TILE - 1) / BIN_TILE;   // 391
    const int nodeBlocks = (N_NODES * 64 + 255) / 256;            // wave/node
    const int tileBlocks = ((N_NODES + 63) / 64);                 // 4 tiles/block

    // CSR build
    k_init <<<1,         128, 0, stream>>>(bcur);
    k_bin  <<<binBlocks, 256, 0, stream>>>(srcv, dstv, bcur, epair);
    k_build<<<NBK,       512, 0, stream>>>(epair, bcur, offsets, esrc);

    // Layer 1 projection
    k_pre1 <<<tileBlocks, 256, 0, stream>>>(x, Wrel1, Wroot1, b1, u1, r1);

    // Fused aggregate-1 + projection-2 (grid-stride, weights amortized)
    k_agg64p2<<<2048, 256, 0, stream>>>(u1, r1, offsets, esrc,
                                        Wrel2, Wroot2, b2, u2, r2);

    // Aggregate layer 2
    k_agg32<<<nodeBlocks, 256, 0, stream>>>(u2, r2, offsets, esrc, out);
}

// Round 8
// 92.874 us; speedup vs baseline: 1.6128x; 1.6128x over previous
//
#include <hip/hip_runtime.h>

static constexpr int N_NODES = 50000;
static constexpr int N_EDGES = 800000;

static constexpr int NBK      = 98;      // buckets of 512 dst-nodes (dst>>9)
static constexpr int BCAP     = 10240;   // slots/bucket (mean 8192, +22 sigma)
static constexpr int MAXE     = BCAP / 512;   // 20 elems/thread in k_build
static constexpr int BIN_TILE = 2048;    // edges per bin block
static constexpr int BIN_BLOCKS = (N_EDGES + BIN_TILE - 1) / BIN_TILE;  // 391
static constexpr int PRE1_TILES  = (N_NODES + 15) / 16;                 // 3125
static constexpr int PRE1_BLOCKS = (PRE1_TILES + 3) / 4;                // 782

typedef __attribute__((ext_vector_type(8))) short   bf16x8;
typedef __attribute__((ext_vector_type(4))) float   floatx4;

// f32 -> bf16 (RNE) as raw u16
__device__ __forceinline__ unsigned short f2b(float f) {
    union { float f; unsigned u; } v; v.f = f;
    unsigned r = v.u + 0x7FFFu + ((v.u >> 16) & 1u);
    return (unsigned short)(r >> 16);
}
__device__ __forceinline__ float blo(unsigned v) {
    union { unsigned u; float f; } c; c.u = v << 16; return c.f;
}
__device__ __forceinline__ float bhi(unsigned v) {
    union { unsigned u; float f; } c; c.u = v & 0xffff0000u; return c.f;
}
__device__ __forceinline__ unsigned pk2(float a, float b) {
    return (unsigned)f2b(a) | ((unsigned)f2b(b) << 16);
}

// ---------------------------------------------------------------------------
// Fused dispatch 1: blocks [0, BIN_BLOCKS) bin edges into dst-buckets;
// blocks [BIN_BLOCKS, +PRE1_BLOCKS) run the MFMA layer-1 projection.
// Independent work -> overlapped on the machine instead of serialized.
// ---------------------------------------------------------------------------
__device__ __forceinline__ void bin_body(
    int bb, const int* __restrict__ srcv, const int* __restrict__ dstv,
    int* __restrict__ bcnt, unsigned* __restrict__ epair)
{
    __shared__ uint2 stage[BIN_TILE];      // 16 KB
    __shared__ int cnt[128];
    __shared__ int scn[128];
    __shared__ int pref[NBK];
    __shared__ int gbase[NBK];

    int tid   = threadIdx.x;
    int base  = bb * BIN_TILE;
    int tileN = min(BIN_TILE, N_EDGES - base);

    if (tid < 128) cnt[tid] = 0;
    __syncthreads();

    int ss[8], dd[8], sl[8];
#pragma unroll
    for (int j = 0; j < 8; ++j) {
        int i = tid + j * 256;
        ss[j] = -1; dd[j] = 0; sl[j] = 0;
        if (i < tileN) {
            ss[j] = srcv[base + i];
            dd[j] = dstv[base + i];
            sl[j] = atomicAdd(&cnt[dd[j] >> 9], 1);   // LDS only
        }
    }
    __syncthreads();

    int own = (tid < 128) ? cnt[tid] : 0;
    if (tid < 128) scn[tid] = own;
    __syncthreads();
    for (int off = 1; off < 128; off <<= 1) {
        int t = 0;
        if (tid < 128 && tid >= off) t = scn[tid - off];
        __syncthreads();
        if (tid < 128) scn[tid] += t;
        __syncthreads();
    }
    if (tid < NBK) {
        pref[tid]  = scn[tid] - cnt[tid];
        gbase[tid] = tid * BCAP + atomicAdd(&bcnt[tid], cnt[tid]);
    }
    __syncthreads();

#pragma unroll
    for (int j = 0; j < 8; ++j) {
        if (ss[j] >= 0) {
            int b = dd[j] >> 9;
            stage[pref[b] + sl[j]] = uint2{(unsigned)ss[j], (unsigned)dd[j]};
        }
    }
    __syncthreads();

    for (int i = tid; i < tileN; i += 256) {
        uint2 pd = stage[i];
        int b = (int)(pd.y >> 9);
        epair[(size_t)gbase[b] + (i - pref[b])] = (pd.x << 9) | (pd.y & 511u);
    }
}

__device__ __forceinline__ void pre1_body(
    int bb, const float* __restrict__ x,
    const float* __restrict__ Wrel, const float* __restrict__ Wroot,
    const float* __restrict__ bias,
    unsigned short* __restrict__ u1, unsigned short* __restrict__ r1)
{
    int lane = threadIdx.x & 63;
    int c15  = lane & 15;
    int q    = lane >> 4;

    bf16x8 bf[2][4][2];
#pragma unroll
    for (int mat = 0; mat < 2; ++mat) {
        const float* W = mat ? Wroot : Wrel;
#pragma unroll
        for (int ct = 0; ct < 4; ++ct) {
            int c = ct * 16 + c15;
#pragma unroll
            for (int kf = 0; kf < 2; ++kf) {
                int kb = kf * 32 + q * 8;
                bf16x8 f;
#pragma unroll
                for (int j = 0; j < 8; ++j)
                    f[j] = (short)f2b(W[(kb + j) * 64 + c]);
                bf[mat][ct][kf] = f;
            }
        }
    }
    float bv[4];
#pragma unroll
    for (int ct = 0; ct < 4; ++ct) bv[ct] = bias[ct * 16 + c15];

    int tile = bb * 4 + (threadIdx.x >> 6);
    if (tile * 16 >= N_NODES) return;
    int row0 = tile * 16;

    const float* xr = x + (size_t)(row0 + c15) * 64;
    bf16x8 a0, a1;
#pragma unroll
    for (int j = 0; j < 8; ++j) {
        a0[j] = (short)f2b(xr[q * 8 + j]);
        a1[j] = (short)f2b(xr[32 + q * 8 + j]);
    }

    floatx4 z = {0.f, 0.f, 0.f, 0.f};
    floatx4 acc[2][4];
#pragma unroll
    for (int mat = 0; mat < 2; ++mat)
#pragma unroll
        for (int ct = 0; ct < 4; ++ct) {
            floatx4 a = __builtin_amdgcn_mfma_f32_16x16x32_bf16(a0, bf[mat][ct][0], z, 0, 0, 0);
            acc[mat][ct] = __builtin_amdgcn_mfma_f32_16x16x32_bf16(a1, bf[mat][ct][1], a, 0, 0, 0);
        }

    // sigma-order write: position p=(lane&15)*4+ct <-> true col ct*16+(lane&15)
#pragma unroll
    for (int reg = 0; reg < 4; ++reg) {
        int row = row0 + q * 4 + reg;
        uint2 uu, rr;
        uu.x = pk2(acc[0][0][reg],          acc[0][1][reg]);
        uu.y = pk2(acc[0][2][reg],          acc[0][3][reg]);
        rr.x = pk2(acc[1][0][reg] + bv[0],  acc[1][1][reg] + bv[1]);
        rr.y = pk2(acc[1][2][reg] + bv[2],  acc[1][3][reg] + bv[3]);
        *reinterpret_cast<uint2*>(u1 + (size_t)row * 64 + c15 * 4) = uu;
        *reinterpret_cast<uint2*>(r1 + (size_t)row * 64 + c15 * 4) = rr;
    }
}

__global__ __launch_bounds__(256) void k_binpre1(
    const int* __restrict__ srcv, const int* __restrict__ dstv,
    int* __restrict__ bcnt, unsigned* __restrict__ epair,
    const float* __restrict__ x,
    const float* __restrict__ Wrel, const float* __restrict__ Wroot,
    const float* __restrict__ bias,
    unsigned short* __restrict__ u1, unsigned short* __restrict__ r1)
{
    if ((int)blockIdx.x < BIN_BLOCKS)
        bin_body(blockIdx.x, srcv, dstv, bcnt, epair);
    else
        pre1_body(blockIdx.x - BIN_BLOCKS, x, Wrel, Wroot, bias, u1, r1);
}

// ---------------------------------------------------------------------------
// Dispatch 2: one block per bucket; single pass over packed pairs held in
// statically-indexed registers; LDS histogram+scan; atomic-free scatter.
// ---------------------------------------------------------------------------
__global__ __launch_bounds__(512) void k_build(
    const unsigned* __restrict__ epair, const int* __restrict__ bcnt,
    int* __restrict__ offsets, int* __restrict__ esrc)
{
    __shared__ int cnt[512];
    __shared__ int scn[512];
    __shared__ int start[512];
    __shared__ int s_base;

    int b = blockIdx.x;
    int t = threadIdx.x;
    int node0 = b << 9;
    int ncnt  = min(512, N_NODES - node0);
    int beg   = b * BCAP;
    int m     = bcnt[b];

    cnt[t] = 0;
    __syncthreads();

    unsigned ev[MAXE]; int sl[MAXE];
#pragma unroll
    for (int j = 0; j < MAXE; ++j) {
        int i = t + j * 512;
        ev[j] = 0; sl[j] = -1;
        if (i < m) {
            ev[j] = epair[beg + i];
            sl[j] = atomicAdd(&cnt[ev[j] & 511u], 1);
        }
    }

    if (t < 64) {
        int m0 = (t      < NBK) ? bcnt[t]      : 0;
        int m1 = (t + 64 < NBK) ? bcnt[t + 64] : 0;
        int pre = ((t < b) ? m0 : 0) + ((t + 64 < b) ? m1 : 0);
        for (int off = 1; off < 64; off <<= 1) pre += __shfl_xor(pre, off);
        if (t == 0) s_base = pre;
    }
    __syncthreads();

    int own = cnt[t];
    scn[t] = own;
    __syncthreads();
    for (int off = 1; off < 512; off <<= 1) {
        int v = (t >= off) ? scn[t - off] : 0;
        __syncthreads();
        scn[t] += v;
        __syncthreads();
    }
    int st = s_base + scn[t] - own;
    start[t] = st;
    if (t < ncnt) offsets[node0 + t] = st;
    if (b == 0 && t == 0) offsets[N_NODES] = N_EDGES;
    __syncthreads();

#pragma unroll
    for (int j = 0; j < MAXE; ++j) {
        if (sl[j] >= 0)
            esrc[start[ev[j] & 511u] + sl[j]] = (int)(ev[j] >> 9);
    }
}

// ---------------------------------------------------------------------------
// Aggregate layer 1 (sigma-order bf16): h = relu(sum u1[src] + r1).
// Wave/node; 8 lanes x uint4 per row; 8 edge slots in flight.
// ---------------------------------------------------------------------------
__global__ __launch_bounds__(256) void k_agg64(
    const unsigned short* __restrict__ u1,
    const unsigned short* __restrict__ r1,
    const int* __restrict__ offsets, const int* __restrict__ esrc,
    unsigned short* __restrict__ h)
{
    int lane = threadIdx.x & 63;
    int node = (blockIdx.x * blockDim.x + threadIdx.x) >> 6;
    if (node >= N_NODES) return;
    int j    = lane & 7;        // 8 lanes/row, 8 ch (16B) each
    int slot = lane >> 3;       // 8 edge slots
    int beg = offsets[node], end = offsets[node + 1];
    float s0 = 0.f, s1 = 0.f, s2 = 0.f, s3 = 0.f;
    float s4 = 0.f, s5 = 0.f, s6 = 0.f, s7 = 0.f;
    for (int e = beg + slot; e < end; e += 8) {
        int sv = esrc[e];
        uint4 v = *reinterpret_cast<const uint4*>(u1 + (size_t)sv * 64 + j * 8);
        s0 += blo(v.x); s1 += bhi(v.x);
        s2 += blo(v.y); s3 += bhi(v.y);
        s4 += blo(v.z); s5 += bhi(v.z);
        s6 += blo(v.w); s7 += bhi(v.w);
    }
    s0 += __shfl_xor(s0, 32); s1 += __shfl_xor(s1, 32);
    s2 += __shfl_xor(s2, 32); s3 += __shfl_xor(s3, 32);
    s4 += __shfl_xor(s4, 32); s5 += __shfl_xor(s5, 32);
    s6 += __shfl_xor(s6, 32); s7 += __shfl_xor(s7, 32);
    s0 += __shfl_xor(s0, 16); s1 += __shfl_xor(s1, 16);
    s2 += __shfl_xor(s2, 16); s3 += __shfl_xor(s3, 16);
    s4 += __shfl_xor(s4, 16); s5 += __shfl_xor(s5, 16);
    s6 += __shfl_xor(s6, 16); s7 += __shfl_xor(s7, 16);
    s0 += __shfl_xor(s0, 8);  s1 += __shfl_xor(s1, 8);
    s2 += __shfl_xor(s2, 8);  s3 += __shfl_xor(s3, 8);
    s4 += __shfl_xor(s4, 8);  s5 += __shfl_xor(s5, 8);
    s6 += __shfl_xor(s6, 8);  s7 += __shfl_xor(s7, 8);
    if (lane < 8) {
        uint4 rv = *reinterpret_cast<const uint4*>(r1 + (size_t)node * 64 + j * 8);
        float v0 = fmaxf(s0 + blo(rv.x), 0.f);
        float v1 = fmaxf(s1 + bhi(rv.x), 0.f);
        float v2 = fmaxf(s2 + blo(rv.y), 0.f);
        float v3 = fmaxf(s3 + bhi(rv.y), 0.f);
        float v4 = fmaxf(s4 + blo(rv.z), 0.f);
        float v5 = fmaxf(s5 + bhi(rv.z), 0.f);
        float v6 = fmaxf(s6 + blo(rv.w), 0.f);
        float v7 = fmaxf(s7 + bhi(rv.w), 0.f);
        uint4 o;
        o.x = pk2(v0, v1); o.y = pk2(v2, v3);
        o.z = pk2(v4, v5); o.w = pk2(v6, v7);
        *reinterpret_cast<uint4*>(h + (size_t)node * 64 + j * 8) = o;
    }
}

// ---------------------------------------------------------------------------
// Layer-2 pre-projection (MFMA), sigma-compensated weights; outputs
// sigma2-order [N][32] bf16 (position 2i <-> col i, 2i+1 <-> col 16+i).
// ---------------------------------------------------------------------------
__global__ __launch_bounds__(256) void k_pre2(
    const unsigned short* __restrict__ h,
    const float* __restrict__ Wrel,    // [64][32] f32
    const float* __restrict__ Wroot,   // [64][32] f32
    const float* __restrict__ bias,    // [32] f32
    unsigned short* __restrict__ u2,
    unsigned short* __restrict__ r2)
{
    int lane = threadIdx.x & 63;
    int c15  = lane & 15;
    int q    = lane >> 4;

    bf16x8 bf[2][2][2];
#pragma unroll
    for (int mat = 0; mat < 2; ++mat) {
        const float* W = mat ? Wroot : Wrel;
#pragma unroll
        for (int ct = 0; ct < 2; ++ct) {
            int c = ct * 16 + c15;
#pragma unroll
            for (int kf = 0; kf < 2; ++kf) {
                bf16x8 f;
#pragma unroll
                for (int j = 0; j < 8; ++j) {
                    int p = kf * 32 + q * 8 + j;
                    int tk = (p & 3) * 16 + (p >> 2);   // sigma(p)
                    f[j] = (short)f2b(W[tk * 32 + c]);
                }
                bf[mat][ct][kf] = f;
            }
        }
    }
    float bv[2];
#pragma unroll
    for (int ct = 0; ct < 2; ++ct) bv[ct] = bias[ct * 16 + c15];

    int tile = (blockIdx.x * blockDim.x + threadIdx.x) >> 6;
    if (tile * 16 >= N_NODES) return;
    int row0 = tile * 16;

    const unsigned short* hr = h + (size_t)(row0 + c15) * 64;
    bf16x8 a0 = *reinterpret_cast<const bf16x8*>(hr + q * 8);
    bf16x8 a1 = *reinterpret_cast<const bf16x8*>(hr + 32 + q * 8);

    floatx4 z = {0.f, 0.f, 0.f, 0.f};
    floatx4 acc[2][2];
#pragma unroll
    for (int mat = 0; mat < 2; ++mat)
#pragma unroll
        for (int ct = 0; ct < 2; ++ct) {
            floatx4 a = __builtin_amdgcn_mfma_f32_16x16x32_bf16(a0, bf[mat][ct][0], z, 0, 0, 0);
            acc[mat][ct] = __builtin_amdgcn_mfma_f32_16x16x32_bf16(a1, bf[mat][ct][1], a, 0, 0, 0);
        }

#pragma unroll
    for (int reg = 0; reg < 4; ++reg) {
        int row = row0 + q * 4 + reg;
        unsigned uu = pk2(acc[0][0][reg],         acc[0][1][reg]);
        unsigned rr = pk2(acc[1][0][reg] + bv[0], acc[1][1][reg] + bv[1]);
        *reinterpret_cast<unsigned*>(u2 + (size_t)row * 32 + c15 * 2) = uu;
        *reinterpret_cast<unsigned*>(r2 + (size_t)row * 32 + c15 * 2) = rr;
    }
}

// ---------------------------------------------------------------------------
// Aggregate layer 2 (sigma2-order bf16 in) -> TRUE row-major f32 out.
// Wave/node; 4 lanes x uint4 per row; 16 edge slots in flight.
// ---------------------------------------------------------------------------
__global__ __launch_bounds__(256) void k_agg32(
    const unsigned short* __restrict__ u2,
    const unsigned short* __restrict__ r2,
    const int* __restrict__ offsets, const int* __restrict__ esrc,
    float* __restrict__ out)
{
    int lane = threadIdx.x & 63;
    int node = (blockIdx.x * blockDim.x + threadIdx.x) >> 6;
    if (node >= N_NODES) return;
    int j    = lane & 3;        // 4 lanes/row, 16B each
    int slot = lane >> 2;       // 16 edge slots
    int beg = offsets[node], end = offsets[node + 1];
    float s0 = 0.f, s1 = 0.f, s2 = 0.f, s3 = 0.f;
    float s4 = 0.f, s5 = 0.f, s6 = 0.f, s7 = 0.f;
    for (int e = beg + slot; e < end; e += 16) {
        int sv = esrc[e];
        uint4 v = *reinterpret_cast<const uint4*>(u2 + (size_t)sv * 32 + j * 8);
        s0 += blo(v.x); s1 += bhi(v.x);
        s2 += blo(v.y); s3 += bhi(v.y);
        s4 += blo(v.z); s5 += bhi(v.z);
        s6 += blo(v.w); s7 += bhi(v.w);
    }
    s0 += __shfl_xor(s0, 32); s1 += __shfl_xor(s1, 32);
    s2 += __shfl_xor(s2, 32); s3 += __shfl_xor(s3, 32);
    s4 += __shfl_xor(s4, 32); s5 += __shfl_xor(s5, 32);
    s6 += __shfl_xor(s6, 32); s7 += __shfl_xor(s7, 32);
    s0 += __shfl_xor(s0, 16); s1 += __shfl_xor(s1, 16);
    s2 += __shfl_xor(s2, 16); s3 += __shfl_xor(s3, 16);
    s4 += __shfl_xor(s4, 16); s5 += __shfl_xor(s5, 16);
    s6 += __shfl_xor(s6, 16); s7 += __shfl_xor(s7, 16);
    s0 += __shfl_xor(s0, 8);  s1 += __shfl_xor(s1, 8);
    s2 += __shfl_xor(s2, 8);  s3 += __shfl_xor(s3, 8);
    s4 += __shfl_xor(s4, 8);  s5 += __shfl_xor(s5, 8);
    s6 += __shfl_xor(s6, 8);  s7 += __shfl_xor(s7, 8);
    s0 += __shfl_xor(s0, 4);  s1 += __shfl_xor(s1, 4);
    s2 += __shfl_xor(s2, 4);  s3 += __shfl_xor(s3, 4);
    s4 += __shfl_xor(s4, 4);  s5 += __shfl_xor(s5, 4);
    s6 += __shfl_xor(s6, 4);  s7 += __shfl_xor(s7, 4);
    if (lane < 4) {
        // sigma2: pair k=j*4+i holds (col k, col 16+k) in (lo,hi)
        uint4 rv = *reinterpret_cast<const uint4*>(r2 + (size_t)node * 32 + j * 8);
        float4 oA, oB;
        oA.x = s0 + blo(rv.x);  oB.x = s1 + bhi(rv.x);
        oA.y = s2 + blo(rv.y);  oB.y = s3 + bhi(rv.y);
        oA.z = s4 + blo(rv.z);  oB.z = s5 + bhi(rv.z);
        oA.w = s6 + blo(rv.w);  oB.w = s7 + bhi(rv.w);
        *reinterpret_cast<float4*>(out + (size_t)node * 32 + j * 4)      = oA;
        *reinterpret_cast<float4*>(out + (size_t)node * 32 + 16 + j * 4) = oB;
    }
}

extern "C" void kernel_launch(void* const* d_in, const int* in_sizes, int n_in,
                              void* d_out, int out_size, void* d_ws, size_t ws_size,
                              hipStream_t stream) {
    const float* x      = (const float*)d_in[0];
    const int*   ei     = (const int*)  d_in[1];
    const float* Wrel1  = (const float*)d_in[2];
    const float* Wroot1 = (const float*)d_in[3];
    const float* b1     = (const float*)d_in[4];
    const float* Wrel2  = (const float*)d_in[5];
    const float* Wroot2 = (const float*)d_in[6];
    const float* b2     = (const float*)d_in[7];
    float*       out    = (float*)d_out;

    const int* srcv = ei;
    const int* dstv = ei + N_EDGES;

    char* p = (char*)d_ws;
    auto alloc = [&](size_t bytes) {
        char* r = p;
        p += (bytes + 255) & ~(size_t)255;
        return r;
    };
    int*      offsets = (int*)     alloc(sizeof(int) * (N_NODES + 1));
    int*      bcnt    = (int*)     alloc(sizeof(int) * NBK);
    unsigned* epair   = (unsigned*)alloc(sizeof(unsigned) * (size_t)NBK * BCAP);
    int*      esrc    = (int*)     alloc(sizeof(int) * N_EDGES);
    unsigned short* u1 = (unsigned short*)alloc(sizeof(short) * (size_t)N_NODES * 64);
    unsigned short* r1 = (unsigned short*)alloc(sizeof(short) * (size_t)N_NODES * 64);
    unsigned short* h  = (unsigned short*)alloc(sizeof(short) * (size_t)N_NODES * 64);
    unsigned short* u2 = (unsigned short*)alloc(sizeof(short) * (size_t)N_NODES * 32);
    unsigned short* r2 = (unsigned short*)alloc(sizeof(short) * (size_t)N_NODES * 32);

    const int nodeBlocks = (N_NODES * 64 + 255) / 256;   // wave per node
    const int tileBlocks = PRE1_BLOCKS;                  // 4 16-row tiles/block

    // CSR build + layer-1 projection (independent -> one fused dispatch)
    hipMemsetAsync(bcnt, 0, sizeof(int) * NBK, stream);
    k_binpre1<<<BIN_BLOCKS + PRE1_BLOCKS, 256, 0, stream>>>(
        srcv, dstv, bcnt, epair, x, Wrel1, Wroot1, b1, u1, r1);
    k_build<<<NBK, 512, 0, stream>>>(epair, bcnt, offsets, esrc);

    // Aggregate layer 1
    k_agg64<<<nodeBlocks, 256, 0, stream>>>(u1, r1, offsets, esrc, h);

    // Layer-2 projection
    k_pre2<<<tileBlocks, 256, 0, stream>>>(h, Wrel2, Wroot2, b2, u2, r2);

    // Aggregate layer 2
    k_agg32<<<nodeBlocks, 256, 0, stream>>>(u2, r2, offsets, esrc, out);
}